// Round 7
// baseline (373.826 us; speedup 1.0000x reference)
//
#include <hip/hip_runtime.h>
#include <hip/hip_bf16.h>
#include <math.h>

#define TID ((int)threadIdx.x)

typedef float f32x4 __attribute__((ext_vector_type(4)));
typedef short s16x8 __attribute__((ext_vector_type(8)));

__device__ __forceinline__ unsigned short f2bf(float f) {
  union { float f; unsigned u; } v; v.f = f;
  unsigned r = v.u + 0x7FFFu + ((v.u >> 16) & 1u);
  return (unsigned short)(r >> 16);
}
__device__ __forceinline__ float bf2f(unsigned short h) {
  union { unsigned u; float f; } v; v.u = ((unsigned)h) << 16;
  return v.f;
}

// ---------------- prep1: We^T->bf16, trig table, K-path vectors ----------------
// wtm layout (512 cols x 256 k, bf16): cols 0..255 = We^T (E), cols 256..511 = Wck^T (prep2)
// ckv[j] = sum_k be[k] g[k] Wk[k][j]; gkv[j] = sum_k g[k] Wk[k][j]; bkv[j] = sum_k bln[k] Wk[k][j] + kb[j]
__global__ __launch_bounds__(256) void prep1_kernel(
    const float* __restrict__ We, const float* __restrict__ Wk,
    const float* __restrict__ g, const float* __restrict__ be,
    const float* __restrict__ bln, const float* __restrict__ kb,
    unsigned short* __restrict__ wtm, float2* __restrict__ trig,
    float* __restrict__ ckv, float* __restrict__ gkv, float* __restrict__ bkv) {
  int blk = blockIdx.x;
  if (blk < 256) {                       // transpose We -> wtm cols 0..255
    int gid = blk * 256 + TID;
    int i = gid >> 8, j = gid & 255;
    wtm[j * 256 + i] = f2bf(We[i * 256 + j]);
  } else if (blk < 512) {                // trig
    int e = (blk - 256) * 256 + TID;     // < 65536 = 4096*16
    int n = e >> 4, p = e & 15;
    float inv = exp2f(-(float)p * 0.8304820237218406f);  // 10000^(-p/16)
    float a = (float)n * inv;
    trig[e] = make_float2(cosf(a), sinf(a));
  } else {                               // vectors (one block)
    int j = TID;
    float a1 = 0.f, a2 = 0.f, a3 = 0.f;
    for (int k = 0; k < 256; ++k) {
      float wkj = Wk[k * 256 + j];       // coalesced across j lanes
      float gk = g[k];
      a1 = fmaf(be[k] * gk, wkj, a1);
      a2 = fmaf(gk, wkj, a2);
      a3 = fmaf(bln[k], wkj, a3);
    }
    ckv[j] = a1; gkv[j] = a2; bkv[j] = a3 + kb[j];
  }
}

// ---------------- prep2: Wck = We . diag(g) . Wk  (fp32), write Wck^T bf16 to wtm cols 256..511 ----------------
__global__ __launch_bounds__(256) void prep2_kernel(
    const float* __restrict__ We, const float* __restrict__ Wk,
    const float* __restrict__ g, unsigned short* __restrict__ wtm) {
  int j = blockIdx.x;                    // output col of Wck
  __shared__ float a[256];
  __shared__ float WeC[256 * 33];        // [i][kk] stride 33 (bank-conflict-free)
  a[TID] = g[TID] * Wk[TID * 256 + j];
  float acc = 0.f;
  for (int k0 = 0; k0 < 256; k0 += 32) {
    __syncthreads();
    const float4* src = (const float4*)&We[TID * 256 + k0];   // 128B contiguous per lane
#pragma unroll
    for (int q4 = 0; q4 < 8; ++q4) {
      float4 v = src[q4];
      WeC[TID * 33 + q4 * 4 + 0] = v.x;
      WeC[TID * 33 + q4 * 4 + 1] = v.y;
      WeC[TID * 33 + q4 * 4 + 2] = v.z;
      WeC[TID * 33 + q4 * 4 + 3] = v.w;
    }
    __syncthreads();
#pragma unroll
    for (int kk = 0; kk < 32; ++kk)
      acc = fmaf(WeC[TID * 33 + kk], a[k0 + kk], acc);
  }
  wtm[(size_t)(256 + j) * 256 + TID] = f2bf(acc);  // coalesced over i=TID
}

// ---------------- query path (unchanged, verified) ----------------
__global__ __launch_bounds__(256) void q_kernel(
    const float* __restrict__ stim_feat, const float* __restrict__ temp_feat,
    const float* __restrict__ stim_w, const float* __restrict__ stim_b,
    const float* __restrict__ temp_w, const float* __restrict__ temp_b,
    const float* __restrict__ q_w, const float* __restrict__ q_b,
    const float* __restrict__ lnq_g, const float* __restrict__ lnq_b,
    float* __restrict__ out_query, float* __restrict__ qhat) {
  int b = blockIdx.x >> 1, q = blockIdx.x & 1;
  __shared__ float f[256];
  __shared__ float red[8];
  const float* feat = (q ? temp_feat : stim_feat) + b * 256;
  const float* W = q ? temp_w : stim_w;
  const float* bias = q ? temp_b : stim_b;
  f[TID] = feat[TID];
  __syncthreads();
  float acc = bias[TID];
#pragma unroll 8
  for (int i = 0; i < 256; ++i) acc = fmaf(f[i], W[i * 256 + TID], acc);
  float s1 = acc, s2 = acc * acc;
#pragma unroll
  for (int m = 1; m < 64; m <<= 1) { s1 += __shfl_xor(s1, m, 64); s2 += __shfl_xor(s2, m, 64); }
  if ((TID & 63) == 0) { red[TID >> 6] = s1; red[4 + (TID >> 6)] = s2; }
  __syncthreads();
  s1 = red[0] + red[1] + red[2] + red[3];
  s2 = red[4] + red[5] + red[6] + red[7];
  float mean = s1 * (1.f / 256.f);
  float var = s2 * (1.f / 256.f) - mean * mean;
  float rstd = rsqrtf(var + 1e-5f);
  float qln = (acc - mean) * rstd * lnq_g[TID] + lnq_b[TID];
  out_query[(b * 2 + q) * 256 + TID] = qln;
  __syncthreads();
  f[TID] = qln;
  __syncthreads();
  float a2 = q_b[TID];
#pragma unroll 8
  for (int i = 0; i < 256; ++i) a2 = fmaf(f[i], q_w[i * 256 + TID], a2);
  __syncthreads();
  f[TID] = a2;
  __syncthreads();
  float partner = f[TID ^ 1];
  int p = (TID >> 1) & 15;
  float inv = exp2f(-(float)p * 0.8304820237218406f);
  float ang = (float)q * inv;
  float cc_ = cosf(ang), ss_ = sinf(ang);
  float r = (TID & 1) ? fmaf(a2, cc_, partner * ss_) : fmaf(a2, cc_, -partner * ss_);
  float sq = r * r;
#pragma unroll
  for (int m = 1; m < 32; m <<= 1) sq += __shfl_xor(sq, m, 32);
  float rs = 1.f / fmaxf(sqrtf(sq), 1e-12f);
  qhat[(b * 2 + q) * 256 + TID] = r * rs;
}

// ---------------- main2: one 512-col GEMM [E | Kraw] -> stats + scores. No X' materialization. ----------------
__global__ __launch_bounds__(256) void main2_kernel(
    const float* __restrict__ x,
    const float* __restrict__ eeg_b,
    const unsigned short* __restrict__ wtm,
    const float2* __restrict__ trig,
    const float* __restrict__ qhat,
    const float* __restrict__ ckv,
    const float* __restrict__ gkv,
    const float* __restrict__ bkv,
    float2* __restrict__ stats,
    float* __restrict__ scores) {

  __shared__ __align__(16) unsigned short A[32 * 256];  // 16KB: X tile, then Kraw (both swizzled)
  __shared__ float CV0[256];
  __shared__ float CV1[256];
  __shared__ float CV2[256];
  __shared__ float QH[512];
  __shared__ float PS[32 * 9];
  __shared__ float2 ST[32];

  const int tid = TID;
  const int w = tid >> 6, l = tid & 63, g = l >> 4, c = l & 15;
  const int r0 = blockIdx.x * 32;
  const int b = r0 >> 12;
  const int n0 = r0 & 4095;

  // ---- stage X (fp32 -> bf16, swizzled) + CV + QH ----
#pragma unroll
  for (int i = 0; i < 4; ++i) {
    int ch = i * 256 + tid;
    int row = ch >> 5, cc = ch & 31;
    const float4* gp = (const float4*)(x + (size_t)(r0 + row) * 256 + cc * 8);
    float4 u0 = gp[0], u1 = gp[1];
    s16x8 pk;
    pk[0] = (short)f2bf(u0.x); pk[1] = (short)f2bf(u0.y);
    pk[2] = (short)f2bf(u0.z); pk[3] = (short)f2bf(u0.w);
    pk[4] = (short)f2bf(u1.x); pk[5] = (short)f2bf(u1.y);
    pk[6] = (short)f2bf(u1.z); pk[7] = (short)f2bf(u1.w);
    *(s16x8*)&A[row * 256 + ((cc ^ (row & 7)) * 8)] = pk;
  }
  CV0[tid] = ckv[tid]; CV1[tid] = gkv[tid]; CV2[tid] = bkv[tid];
  QH[tid] = qhat[(size_t)b * 512 + tid];
  QH[256 + tid] = qhat[(size_t)b * 512 + 256 + tid];
  __syncthreads();

  // ---- combined GEMM: wave w owns cols [w*128, w*128+128) of [We | Wck] ----
  f32x4 acc[2][8];
#pragma unroll
  for (int rb = 0; rb < 2; ++rb)
#pragma unroll
    for (int cb = 0; cb < 8; ++cb) acc[rb][cb] = (f32x4){0.f, 0.f, 0.f, 0.f};
#pragma unroll
  for (int ks = 0; ks < 8; ++ks) {
    s16x8 af[2];
#pragma unroll
    for (int rb = 0; rb < 2; ++rb) {
      int row = rb * 16 + c; int kc = ks * 4 + g;
      af[rb] = *(const s16x8*)&A[row * 256 + ((kc ^ (row & 7)) * 8)];
    }
#pragma unroll
    for (int hb = 0; hb < 2; ++hb) {
      s16x8 bf4[4];
#pragma unroll
      for (int q4 = 0; q4 < 4; ++q4) {
        int col = w * 128 + (hb * 4 + q4) * 16 + c;
        bf4[q4] = *(const s16x8*)&wtm[(size_t)col * 256 + ks * 32 + g * 8];
      }
#pragma unroll
      for (int rb = 0; rb < 2; ++rb)
#pragma unroll
        for (int q4 = 0; q4 < 4; ++q4)
          acc[rb][hb * 4 + q4] = __builtin_amdgcn_mfma_f32_16x16x32_bf16(
              af[rb], bf4[q4], acc[rb][hb * 4 + q4], 0, 0, 0);
    }
  }

  // ---- LN stats over the E half (waves 0,1) ----
  if (w < 2) {
    float ebias[8];
#pragma unroll
    for (int cb = 0; cb < 8; ++cb) ebias[cb] = eeg_b[w * 128 + cb * 16 + c];
    float ps[2][4], pq[2][4];
#pragma unroll
    for (int rb = 0; rb < 2; ++rb)
#pragma unroll
      for (int r = 0; r < 4; ++r) {
        float s = 0.f, q2 = 0.f;
#pragma unroll
        for (int cb = 0; cb < 8; ++cb) {
          float v = acc[rb][cb][r] + ebias[cb];
          s += v; q2 += v * v;
        }
        ps[rb][r] = s; pq[rb][r] = q2;
      }
#pragma unroll
    for (int m = 1; m < 16; m <<= 1)
#pragma unroll
      for (int rb = 0; rb < 2; ++rb)
#pragma unroll
        for (int r = 0; r < 4; ++r) {
          ps[rb][r] += __shfl_xor(ps[rb][r], m, 64);
          pq[rb][r] += __shfl_xor(pq[rb][r], m, 64);
        }
    float outS = 0.f, outQ = 0.f;
#pragma unroll
    for (int rb = 0; rb < 2; ++rb)
#pragma unroll
      for (int r = 0; r < 4; ++r)
        if (c == rb * 4 + r) { outS = ps[rb][r]; outQ = pq[rb][r]; }
    if (c < 8) {
      int row = (c >> 2) * 16 + g * 4 + (c & 3);
      PS[row * 9 + w * 2 + 0] = outS;
      PS[row * 9 + w * 2 + 1] = outQ;
    }
  }
  __syncthreads();   // all GEMM A-reads done; PS complete

  if (tid < 32) {
    float s = PS[tid * 9 + 0] + PS[tid * 9 + 2];
    float q2 = PS[tid * 9 + 1] + PS[tid * 9 + 3];
    float mean = s * (1.f / 256.f);
    float var = q2 * (1.f / 256.f) - mean * mean;
    float rstd = rsqrtf(var + 1e-5f);
    ST[tid] = make_float2(mean, rstd);
    stats[(size_t)r0 + tid] = make_float2(mean, rstd);
  }
  if (w >= 2) {
    // ---- Kraw -> A (raw, swizzled); affine deferred to score phase ----
#pragma unroll
    for (int rb = 0; rb < 2; ++rb)
#pragma unroll
      for (int r = 0; r < 4; ++r) {
        int row = rb * 16 + g * 4 + r;
#pragma unroll
        for (int cb = 0; cb < 8; ++cb) {
          int kcol = (w - 2) * 128 + cb * 16 + c;
          A[row * 256 + (kcol ^ ((row & 7) * 8))] = f2bf(acc[rb][cb][r]);
        }
      }
  }
  __syncthreads();

  // ---- score phase: K = Kraw*rstd + affine(col,row) -> RoPE -> l2norm -> dots ----
  {
    int h = tid >> 5, row = tid & 31;
    float2 st = ST[row];
    float is = st.y, mis = st.x * st.y;
    const float2* tgp = trig + (size_t)(n0 + row) * 16;
    float ssq = 0.f, d0 = 0.f, d1 = 0.f;
#pragma unroll
    for (int j = 0; j < 4; ++j) {
      int u = h * 4 + j;
      s16x8 kvv = *(const s16x8*)&A[row * 256 + ((u ^ (row & 7)) * 8)];
      float2 t0 = tgp[j * 4 + 0], t1 = tgp[j * 4 + 1], t2 = tgp[j * 4 + 2], t3 = tgp[j * 4 + 3];
      float2 tg4[4] = {t0, t1, t2, t3};
#pragma unroll
      for (int t = 0; t < 4; ++t) {
        int col = h * 32 + j * 8 + 2 * t;
        float base0 = fmaf(CV0[col], is, fmaf(-mis, CV1[col], CV2[col]));
        float base1 = fmaf(CV0[col + 1], is, fmaf(-mis, CV1[col + 1], CV2[col + 1]));
        float k0 = fmaf(bf2f((unsigned short)kvv[2 * t]), is, base0);
        float k1 = fmaf(bf2f((unsigned short)kvv[2 * t + 1]), is, base1);
        float2 cs = tg4[t];
        float rv0 = k0 * cs.x - k1 * cs.y;
        float rv1 = fmaf(k1, cs.x, k0 * cs.y);
        ssq = fmaf(rv0, rv0, fmaf(rv1, rv1, ssq));
        d0 = fmaf(rv0, QH[col], fmaf(rv1, QH[col + 1], d0));
        d1 = fmaf(rv0, QH[256 + col], fmaf(rv1, QH[256 + col + 1], d1));
      }
    }
    float isv = 0.17677669529663687f / fmaxf(sqrtf(ssq), 1e-12f);
    scores[(size_t)((b * 8 + h) * 2 + 0) * 4096 + n0 + row] = d0 * isv;
    scores[(size_t)((b * 8 + h) * 2 + 1) * 4096 + n0 + row] = d1 * isv;
  }
}

// ---------------- wgt: stats -> tanh rescale -> softmax -> w~ = w*rstd, scalars S1,S2 ----------------
__global__ __launch_bounds__(256) void wgt_kernel(
    const float* __restrict__ scores, const float2* __restrict__ stats,
    float* __restrict__ wbuf, float2* __restrict__ sbuf) {
  int b = blockIdx.x >> 3, h = blockIdx.x & 7;
  const float* s0p = scores + (size_t)((b * 8 + h) * 2 + 0) * 4096;
  const float* s1p = scores + (size_t)((b * 8 + h) * 2 + 1) * 4096;
  float sa[16], sb[16];
  float a1 = 0.f, a2 = 0.f, b1 = 0.f, b2 = 0.f;
#pragma unroll
  for (int i = 0; i < 16; ++i) {
    int k = i * 256 + TID;
    sa[i] = s0p[k]; sb[i] = s1p[k];
    a1 += sa[i]; a2 += sa[i] * sa[i];
    b1 += sb[i]; b2 += sb[i] * sb[i];
  }
  __shared__ float red[16];
  int w = TID >> 6;
#pragma unroll
  for (int m = 1; m < 64; m <<= 1) {
    a1 += __shfl_xor(a1, m, 64); a2 += __shfl_xor(a2, m, 64);
    b1 += __shfl_xor(b1, m, 64); b2 += __shfl_xor(b2, m, 64);
  }
  if ((TID & 63) == 0) { red[w * 4] = a1; red[w * 4 + 1] = a2; red[w * 4 + 2] = b1; red[w * 4 + 3] = b2; }
  __syncthreads();
  a1 = red[0] + red[4] + red[8] + red[12];
  a2 = red[1] + red[5] + red[9] + red[13];
  b1 = red[2] + red[6] + red[10] + red[14];
  b2 = red[3] + red[7] + red[11] + red[15];
  float va = (a2 - a1 * a1 * (1.f / 4096.f)) * (1.f / 4095.f);   // ddof=1
  float vb = (b2 - b1 * b1 * (1.f / 4096.f)) * (1.f / 4095.f);
  float sga = fmaxf(sqrtf(fmaxf(va, 0.f)), 1e-3f);
  float sgb = fmaxf(sqrtf(fmaxf(vb, 0.f)), 1e-3f);
  float ia = 0.5f / sga, ib = 0.5f / sgb;
  float fa = 5.f * sga, fb = 5.f * sgb;
  float ea = 0.f, eb = 0.f;
#pragma unroll
  for (int i = 0; i < 16; ++i) {
    sa[i] = __expf(tanhf(sa[i] * ia) * fa);    // |arg| <= 5*sigma: no max-sub needed
    sb[i] = __expf(tanhf(sb[i] * ib) * fb);
    ea += sa[i]; eb += sb[i];
  }
#pragma unroll
  for (int m = 1; m < 64; m <<= 1) { ea += __shfl_xor(ea, m, 64); eb += __shfl_xor(eb, m, 64); }
  __syncthreads();
  if ((TID & 63) == 0) { red[w * 2] = ea; red[w * 2 + 1] = eb; }
  __syncthreads();
  ea = red[0] + red[2] + red[4] + red[6];
  eb = red[1] + red[3] + red[5] + red[7];
  float iea = 1.f / ea, ieb = 1.f / eb;   // denom (1+1e-8) == 1.0f in fp32
  float* w0 = wbuf + ((size_t)(b * 16) + h * 2 + 0) * 4096;
  float* w1 = w0 + 4096;
  float s1a = 0.f, s2a = 0.f, s1b = 0.f, s2b = 0.f;
#pragma unroll
  for (int i = 0; i < 16; ++i) {
    int k = i * 256 + TID;
    float2 st = stats[(size_t)b * 4096 + k];
    float wa = fmaf(sa[i], iea, 1e-4f);
    float wb = fmaf(sb[i], ieb, 1e-4f);
    float wta = wa * st.y, wtb = wb * st.y;
    w0[k] = wta; w1[k] = wtb;
    s1a += wta; s2a = fmaf(wta, st.x, s2a);
    s1b += wtb; s2b = fmaf(wtb, st.x, s2b);
  }
#pragma unroll
  for (int m = 1; m < 64; m <<= 1) {
    s1a += __shfl_xor(s1a, m, 64); s2a += __shfl_xor(s2a, m, 64);
    s1b += __shfl_xor(s1b, m, 64); s2b += __shfl_xor(s2b, m, 64);
  }
  __syncthreads();
  if ((TID & 63) == 0) { red[w * 4] = s1a; red[w * 4 + 1] = s2a; red[w * 4 + 2] = s1b; red[w * 4 + 3] = s2b; }
  __syncthreads();
  if (TID == 0) {
    sbuf[((size_t)(b * 8 + h)) * 2 + 0] =
        make_float2(red[0] + red[4] + red[8] + red[12], red[1] + red[5] + red[9] + red[13]);
    sbuf[((size_t)(b * 8 + h)) * 2 + 1] =
        make_float2(red[2] + red[6] + red[10] + red[14], red[3] + red[7] + red[11] + red[15]);
  }
}

// ---------------- ysum: yin partials = sum_n w~[n] * X_in[n,:] (fp32 input, exact) ----------------
__global__ __launch_bounds__(256) void ysum_kernel(
    const float* __restrict__ x, const float* __restrict__ wbuf,
    float* __restrict__ ypart) {
  int b = blockIdx.x >> 5, slab = blockIdx.x & 31;
  int h = TID >> 5, cg = TID & 31;                 // 8 heads x 32 col-groups
  const float* xb = x + ((size_t)(b * 4096 + slab * 128)) * 256 + cg * 8;
  const float* w0 = wbuf + ((size_t)(b * 16) + h * 2 + 0) * 4096 + slab * 128;
  const float* w1 = w0 + 4096;
  float y0[8], y1[8];
#pragma unroll
  for (int t = 0; t < 8; ++t) { y0[t] = 0.f; y1[t] = 0.f; }
#pragma unroll 4
  for (int r = 0; r < 128; ++r) {
    const float4* fp = (const float4*)(xb + (size_t)r * 256);
    float4 va = fp[0], vb4 = fp[1];
    float wa = w0[r], wc = w1[r];
    y0[0] = fmaf(wa, va.x, y0[0]);  y1[0] = fmaf(wc, va.x, y1[0]);
    y0[1] = fmaf(wa, va.y, y0[1]);  y1[1] = fmaf(wc, va.y, y1[1]);
    y0[2] = fmaf(wa, va.z, y0[2]);  y1[2] = fmaf(wc, va.z, y1[2]);
    y0[3] = fmaf(wa, va.w, y0[3]);  y1[3] = fmaf(wc, va.w, y1[3]);
    y0[4] = fmaf(wa, vb4.x, y0[4]); y1[4] = fmaf(wc, vb4.x, y1[4]);
    y0[5] = fmaf(wa, vb4.y, y0[5]); y1[5] = fmaf(wc, vb4.y, y1[5]);
    y0[6] = fmaf(wa, vb4.z, y0[6]); y1[6] = fmaf(wc, vb4.z, y1[6]);
    y0[7] = fmaf(wa, vb4.w, y0[7]); y1[7] = fmaf(wc, vb4.w, y1[7]);
  }
  float* yp = ypart + (((size_t)(b * 32 + slab) * 16) + h * 2) * 256 + cg * 8;
  *(float4*)&yp[0] = (float4){y0[0], y0[1], y0[2], y0[3]};
  *(float4*)&yp[4] = (float4){y0[4], y0[5], y0[6], y0[7]};
  *(float4*)&yp[256] = (float4){y1[0], y1[1], y1[2], y1[3]};
  *(float4*)&yp[260] = (float4){y1[4], y1[5], y1[6], y1[7]};
}

// ---------------- finish: reduce yin; z = (yin.We + S1.be - S2).g + 1.4096*bln; attn = z.Wv + 1.4096*vb ----------------
__global__ __launch_bounds__(256) void finish_kernel(
    const float* __restrict__ ypart, const float2* __restrict__ sbuf,
    const float* __restrict__ We, const float* __restrict__ be,
    const float* __restrict__ g, const float* __restrict__ bln,
    const float* __restrict__ v_w, const float* __restrict__ v_b,
    const float* __restrict__ fc_w, const float* __restrict__ fc_b,
    float* __restrict__ out_attn, float* __restrict__ out_pooled,
    float* __restrict__ out_logits) {
  int b = blockIdx.x;
  __shared__ float Y[16][256];
  __shared__ float Z[16][257];
  __shared__ float ATT[2][256];
  __shared__ float P[256];
  for (int idx = TID; idx < 4096; idx += 256) {
    int hq = idx >> 8, cc = idx & 255;
    float s = 0.f;
#pragma unroll 8
    for (int sl = 0; sl < 32; ++sl)
      s += ypart[(((size_t)(b * 32 + sl) * 16) + hq) * 256 + cc];
    Y[hq][cc] = s;
  }
  __syncthreads();
#pragma unroll
  for (int o4 = 0; o4 < 16; ++o4) {
    int hq = o4, k = TID;
    float2 s12 = sbuf[(size_t)b * 16 + hq];
    float t = s12.x * be[k];
#pragma unroll 8
    for (int cc = 0; cc < 256; ++cc)
      t = fmaf(Y[hq][cc], We[cc * 256 + k], t);
    Z[hq][k] = (t - s12.y) * g[k] + 1.4096f * bln[k];
  }
  __syncthreads();
#pragma unroll
  for (int o = TID; o < 512; o += 256) {
    int q = o >> 8, dout = o & 255;
    int hq = (dout >> 5) * 2 + q;
    float acc = 1.4096f * v_b[dout];
#pragma unroll 8
    for (int cc = 0; cc < 256; ++cc)
      acc = fmaf(Z[hq][cc], v_w[cc * 256 + dout], acc);
    out_attn[(b * 2 + q) * 256 + dout] = acc;
    ATT[q][dout] = acc;
  }
  __syncthreads();
  float p = 0.5f * (ATT[0][TID] + ATT[1][TID]);
  out_pooled[b * 256 + TID] = p;
  P[TID] = p;
  __syncthreads();
  if (TID < 40) {
    float acc = fc_b[TID];
#pragma unroll 8
    for (int i = 0; i < 256; ++i) acc = fmaf(P[i], fc_w[i * 40 + TID], acc);
    out_logits[b * 40 + TID] = acc;
  }
}

extern "C" void kernel_launch(void* const* d_in, const int* in_sizes, int n_in,
                              void* d_out, int out_size, void* d_ws, size_t ws_size,
                              hipStream_t stream) {
  (void)in_sizes; (void)n_in; (void)out_size; (void)ws_size;
  const float* eeg_feat  = (const float*)d_in[0];
  const float* stim_feat = (const float*)d_in[1];
  const float* temp_feat = (const float*)d_in[2];
  const float* eeg_w = (const float*)d_in[3];
  const float* eeg_b = (const float*)d_in[4];
  const float* stim_w = (const float*)d_in[5];
  const float* stim_b = (const float*)d_in[6];
  const float* temp_w = (const float*)d_in[7];
  const float* temp_b = (const float*)d_in[8];
  const float* q_w = (const float*)d_in[9];
  const float* q_b = (const float*)d_in[10];
  const float* k_w = (const float*)d_in[11];
  const float* k_b = (const float*)d_in[12];
  const float* v_w = (const float*)d_in[13];
  const float* v_b = (const float*)d_in[14];
  const float* fc_w = (const float*)d_in[15];
  const float* fc_b = (const float*)d_in[16];
  const float* lnq_g = (const float*)d_in[17];
  const float* lnq_b = (const float*)d_in[18];
  const float* lnk_g = (const float*)d_in[19];
  const float* lnk_b = (const float*)d_in[20];

  char* ws = (char*)d_ws;
  unsigned short* wtm = (unsigned short*)(ws + 0);          // 256 KB ([We^T | Wck^T] bf16)
  float2* trig        = (float2*)(ws + 262144);             // 512 KB
  float* qhat         = (float*)(ws + 786432);              // 64 KB
  float* ckv          = (float*)(ws + 851968);              // 1 KB
  float* gkv          = (float*)(ws + 852992);              // 1 KB
  float* bkv          = (float*)(ws + 854016);              // 1 KB
  float2* sbuf        = (float2*)(ws + 855040);             // 4 KB
  float2* stats       = (float2*)(ws + 1048576);            // 1 MB
  float* scores       = (float*)(ws + 2097152);             // 8 MB
  float* wbuf         = (float*)(ws + 10485760);            // 8 MB
  float* ypart        = (float*)(ws + 18874368);            // 16 MB

  float* out = (float*)d_out;
  float* out_logits = out;                 // 32*40
  float* out_pooled = out + 1280;          // 32*256
  float* out_attn   = out + 9472;          // 32*2*256
  float* out_query  = out + 25856;         // 32*2*256

  prep1_kernel<<<513, 256, 0, stream>>>(eeg_w, k_w, lnk_g, eeg_b, lnk_b, k_b,
                                        wtm, trig, ckv, gkv, bkv);
  prep2_kernel<<<256, 256, 0, stream>>>(eeg_w, k_w, lnk_g, wtm);
  q_kernel<<<64, 256, 0, stream>>>(stim_feat, temp_feat, stim_w, stim_b,
                                   temp_w, temp_b, q_w, q_b, lnq_g, lnq_b,
                                   out_query, qhat);
  main2_kernel<<<4096, 256, 0, stream>>>(eeg_feat, eeg_b, wtm, trig, qhat,
                                         ckv, gkv, bkv, stats, scores);
  wgt_kernel<<<256, 256, 0, stream>>>(scores, stats, wbuf, sbuf);
  ysum_kernel<<<1024, 256, 0, stream>>>(eeg_feat, wbuf, ypart);
  finish_kernel<<<32, 256, 0, stream>>>(ypart, sbuf, eeg_w, eeg_b, lnk_g, lnk_b,
                                        v_w, v_b, fc_w, fc_b,
                                        out_attn, out_pooled, out_logits);
}

// Round 8
// 306.028 us; speedup vs baseline: 1.2215x; 1.2215x over previous
//
#include <hip/hip_runtime.h>
#include <hip/hip_bf16.h>
#include <math.h>

#define TID ((int)threadIdx.x)

typedef float f32x4 __attribute__((ext_vector_type(4)));
typedef short s16x8 __attribute__((ext_vector_type(8)));

__device__ __forceinline__ unsigned short f2bf(float f) {
  union { float f; unsigned u; } v; v.f = f;
  unsigned r = v.u + 0x7FFFu + ((v.u >> 16) & 1u);
  return (unsigned short)(r >> 16);
}
__device__ __forceinline__ float bf2f(unsigned short h) {
  union { unsigned u; float f; } v; v.u = ((unsigned)h) << 16;
  return v.f;
}

// ---------------- prep1: We -> wf fragment layout, trig table, K-path vectors ----------------
// wf fragment layout: wf[((cbG*8 + ks)*64 + lane)*8 + e] = W[k][col],
//   col = cbG*16 + (lane&15), k = ks*32 + (lane>>4)*8 + e.  cbG 0..15 = We, 16..31 = Wck.
// A wave's B-fragment load (64 lanes x 16B) is 1KB CONTIGUOUS -> fully coalesced.
__global__ __launch_bounds__(256) void prep1_kernel(
    const float* __restrict__ We, const float* __restrict__ Wk,
    const float* __restrict__ g, const float* __restrict__ be,
    const float* __restrict__ bln, const float* __restrict__ kb,
    unsigned short* __restrict__ wf, float2* __restrict__ trig,
    float* __restrict__ ckv, float* __restrict__ gkv, float* __restrict__ bkv) {
  int blk = blockIdx.x;
  if (blk < 32) {                        // We -> fragment layout (cbG 0..15)
    int fi = blk * 256 + TID;            // [0, 8192)
    int l = fi & 63, ks = (fi >> 6) & 7, cbG = fi >> 9;
    int col = cbG * 16 + (l & 15);
    int kbase = ks * 32 + ((l >> 4) & 3) * 8;
    s16x8 pk;
#pragma unroll
    for (int e = 0; e < 8; ++e) pk[e] = (short)f2bf(We[(size_t)(kbase + e) * 256 + col]);
    *(s16x8*)&wf[(size_t)fi * 8] = pk;
  } else if (blk < 288) {                // trig
    int e = (blk - 32) * 256 + TID;      // < 65536 = 4096*16
    int n = e >> 4, p = e & 15;
    float inv = exp2f(-(float)p * 0.8304820237218406f);  // 10000^(-p/16)
    float a = (float)n * inv;
    trig[e] = make_float2(cosf(a), sinf(a));
  } else {                               // vectors (one block)
    int j = TID;
    float a1 = 0.f, a2 = 0.f, a3 = 0.f;
    for (int k = 0; k < 256; ++k) {
      float wkj = Wk[k * 256 + j];       // coalesced across j lanes
      float gk = g[k];
      a1 = fmaf(be[k] * gk, wkj, a1);
      a2 = fmaf(gk, wkj, a2);
      a3 = fmaf(bln[k], wkj, a3);
    }
    ckv[j] = a1; gkv[j] = a2; bkv[j] = a3 + kb[j];
  }
}

// ---------------- prep2: Wck = We . diag(g) . Wk (fp32) -> wf fragment layout (cbG 16..31) ----------------
__global__ __launch_bounds__(256) void prep2_kernel(
    const float* __restrict__ We, const float* __restrict__ Wk,
    const float* __restrict__ g, unsigned short* __restrict__ wf) {
  int j = blockIdx.x;                    // output col of Wck
  __shared__ float a[256];
  __shared__ float WeC[256 * 33];        // [i][kk] stride 33 (bank-conflict-free)
  a[TID] = g[TID] * Wk[TID * 256 + j];
  float acc = 0.f;
  for (int k0 = 0; k0 < 256; k0 += 32) {
    __syncthreads();
    const float4* src = (const float4*)&We[TID * 256 + k0];
#pragma unroll
    for (int q4 = 0; q4 < 8; ++q4) {
      float4 v = src[q4];
      WeC[TID * 33 + q4 * 4 + 0] = v.x;
      WeC[TID * 33 + q4 * 4 + 1] = v.y;
      WeC[TID * 33 + q4 * 4 + 2] = v.z;
      WeC[TID * 33 + q4 * 4 + 3] = v.w;
    }
    __syncthreads();
#pragma unroll
    for (int kk = 0; kk < 32; ++kk)
      acc = fmaf(WeC[TID * 33 + kk], a[k0 + kk], acc);
  }
  // Wck[TID][j] -> fragment position
  int cbG = 16 + (j >> 4), c = j & 15;
  int ks = TID >> 5, g3 = (TID >> 3) & 3, e = TID & 7;
  size_t pos = (((size_t)(cbG * 8 + ks) * 64) + g3 * 16 + c) * 8 + e;
  wf[pos] = f2bf(acc);
}

// ---------------- query path (unchanged, verified) ----------------
__global__ __launch_bounds__(256) void q_kernel(
    const float* __restrict__ stim_feat, const float* __restrict__ temp_feat,
    const float* __restrict__ stim_w, const float* __restrict__ stim_b,
    const float* __restrict__ temp_w, const float* __restrict__ temp_b,
    const float* __restrict__ q_w, const float* __restrict__ q_b,
    const float* __restrict__ lnq_g, const float* __restrict__ lnq_b,
    float* __restrict__ out_query, float* __restrict__ qhat) {
  int b = blockIdx.x >> 1, q = blockIdx.x & 1;
  __shared__ float f[256];
  __shared__ float red[8];
  const float* feat = (q ? temp_feat : stim_feat) + b * 256;
  const float* W = q ? temp_w : stim_w;
  const float* bias = q ? temp_b : stim_b;
  f[TID] = feat[TID];
  __syncthreads();
  float acc = bias[TID];
#pragma unroll 8
  for (int i = 0; i < 256; ++i) acc = fmaf(f[i], W[i * 256 + TID], acc);
  float s1 = acc, s2 = acc * acc;
#pragma unroll
  for (int m = 1; m < 64; m <<= 1) { s1 += __shfl_xor(s1, m, 64); s2 += __shfl_xor(s2, m, 64); }
  if ((TID & 63) == 0) { red[TID >> 6] = s1; red[4 + (TID >> 6)] = s2; }
  __syncthreads();
  s1 = red[0] + red[1] + red[2] + red[3];
  s2 = red[4] + red[5] + red[6] + red[7];
  float mean = s1 * (1.f / 256.f);
  float var = s2 * (1.f / 256.f) - mean * mean;
  float rstd = rsqrtf(var + 1e-5f);
  float qln = (acc - mean) * rstd * lnq_g[TID] + lnq_b[TID];
  out_query[(b * 2 + q) * 256 + TID] = qln;
  __syncthreads();
  f[TID] = qln;
  __syncthreads();
  float a2 = q_b[TID];
#pragma unroll 8
  for (int i = 0; i < 256; ++i) a2 = fmaf(f[i], q_w[i * 256 + TID], a2);
  __syncthreads();
  f[TID] = a2;
  __syncthreads();
  float partner = f[TID ^ 1];
  int p = (TID >> 1) & 15;
  float inv = exp2f(-(float)p * 0.8304820237218406f);
  float ang = (float)q * inv;
  float cc_ = cosf(ang), ss_ = sinf(ang);
  float r = (TID & 1) ? fmaf(a2, cc_, partner * ss_) : fmaf(a2, cc_, -partner * ss_);
  float sq = r * r;
#pragma unroll
  for (int m = 1; m < 32; m <<= 1) sq += __shfl_xor(sq, m, 32);
  float rs = 1.f / fmaxf(sqrtf(sq), 1e-12f);
  qhat[(b * 2 + q) * 256 + TID] = r * rs;
}

// ---------------- main2: one 512-col GEMM [E | Kraw] -> stats + scores (coalesced B) ----------------
__global__ __launch_bounds__(256) void main2_kernel(
    const float* __restrict__ x,
    const float* __restrict__ eeg_b,
    const unsigned short* __restrict__ wf,
    const float2* __restrict__ trig,
    const float* __restrict__ qhat,
    const float* __restrict__ ckv,
    const float* __restrict__ gkv,
    const float* __restrict__ bkv,
    float2* __restrict__ stats,
    float* __restrict__ scores) {

  __shared__ __align__(16) unsigned short A[32 * 256];  // 16KB: X tile, then Kraw (both swizzled)
  __shared__ float CV0[256];
  __shared__ float CV1[256];
  __shared__ float CV2[256];
  __shared__ float QH[512];
  __shared__ float PS[32 * 9];
  __shared__ float2 ST[32];

  const int tid = TID;
  const int w = tid >> 6, l = tid & 63, g = l >> 4, c = l & 15;
  const int r0 = blockIdx.x * 32;
  const int b = r0 >> 12;
  const int n0 = r0 & 4095;

  // ---- stage X (fp32 -> bf16, swizzled) + CV + QH ----
#pragma unroll
  for (int i = 0; i < 4; ++i) {
    int ch = i * 256 + tid;
    int row = ch >> 5, cc = ch & 31;
    const float4* gp = (const float4*)(x + (size_t)(r0 + row) * 256 + cc * 8);
    float4 u0 = gp[0], u1 = gp[1];
    s16x8 pk;
    pk[0] = (short)f2bf(u0.x); pk[1] = (short)f2bf(u0.y);
    pk[2] = (short)f2bf(u0.z); pk[3] = (short)f2bf(u0.w);
    pk[4] = (short)f2bf(u1.x); pk[5] = (short)f2bf(u1.y);
    pk[6] = (short)f2bf(u1.z); pk[7] = (short)f2bf(u1.w);
    *(s16x8*)&A[row * 256 + ((cc ^ (row & 7)) * 8)] = pk;
  }
  CV0[tid] = ckv[tid]; CV1[tid] = gkv[tid]; CV2[tid] = bkv[tid];
  QH[tid] = qhat[(size_t)b * 512 + tid];
  QH[256 + tid] = qhat[(size_t)b * 512 + 256 + tid];
  __syncthreads();

  // ---- combined GEMM: wave w owns cols [w*128, w*128+128) of [We | Wck] ----
  f32x4 acc[2][8];
#pragma unroll
  for (int rb = 0; rb < 2; ++rb)
#pragma unroll
    for (int cb = 0; cb < 8; ++cb) acc[rb][cb] = (f32x4){0.f, 0.f, 0.f, 0.f};
#pragma unroll
  for (int ks = 0; ks < 8; ++ks) {
    s16x8 af[2];
#pragma unroll
    for (int rb = 0; rb < 2; ++rb) {
      int row = rb * 16 + c; int kc = ks * 4 + g;
      af[rb] = *(const s16x8*)&A[row * 256 + ((kc ^ (row & 7)) * 8)];
    }
#pragma unroll
    for (int hb = 0; hb < 2; ++hb) {
      s16x8 bf4[4];
#pragma unroll
      for (int q4 = 0; q4 < 4; ++q4) {
        int cbG = w * 8 + hb * 4 + q4;
        bf4[q4] = *(const s16x8*)&wf[(size_t)((cbG * 8 + ks) * 64 + l) * 8];  // 1KB contiguous/wave
      }
#pragma unroll
      for (int rb = 0; rb < 2; ++rb)
#pragma unroll
        for (int q4 = 0; q4 < 4; ++q4)
          acc[rb][hb * 4 + q4] = __builtin_amdgcn_mfma_f32_16x16x32_bf16(
              af[rb], bf4[q4], acc[rb][hb * 4 + q4], 0, 0, 0);
    }
  }

  // ---- LN stats over the E half (waves 0,1) ----
  if (w < 2) {
    float ebias[8];
#pragma unroll
    for (int cb = 0; cb < 8; ++cb) ebias[cb] = eeg_b[w * 128 + cb * 16 + c];
    float ps[2][4], pq[2][4];
#pragma unroll
    for (int rb = 0; rb < 2; ++rb)
#pragma unroll
      for (int r = 0; r < 4; ++r) {
        float s = 0.f, q2 = 0.f;
#pragma unroll
        for (int cb = 0; cb < 8; ++cb) {
          float v = acc[rb][cb][r] + ebias[cb];
          s += v; q2 += v * v;
        }
        ps[rb][r] = s; pq[rb][r] = q2;
      }
#pragma unroll
    for (int m = 1; m < 16; m <<= 1)
#pragma unroll
      for (int rb = 0; rb < 2; ++rb)
#pragma unroll
        for (int r = 0; r < 4; ++r) {
          ps[rb][r] += __shfl_xor(ps[rb][r], m, 64);
          pq[rb][r] += __shfl_xor(pq[rb][r], m, 64);
        }
    float outS = 0.f, outQ = 0.f;
#pragma unroll
    for (int rb = 0; rb < 2; ++rb)
#pragma unroll
      for (int r = 0; r < 4; ++r)
        if (c == rb * 4 + r) { outS = ps[rb][r]; outQ = pq[rb][r]; }
    if (c < 8) {
      int row = (c >> 2) * 16 + g * 4 + (c & 3);
      PS[row * 9 + w * 2 + 0] = outS;
      PS[row * 9 + w * 2 + 1] = outQ;
    }
  }
  __syncthreads();   // all GEMM A-reads done; PS complete

  if (tid < 32) {
    float s = PS[tid * 9 + 0] + PS[tid * 9 + 2];
    float q2 = PS[tid * 9 + 1] + PS[tid * 9 + 3];
    float mean = s * (1.f / 256.f);
    float var = q2 * (1.f / 256.f) - mean * mean;
    float rstd = rsqrtf(var + 1e-5f);
    ST[tid] = make_float2(mean, rstd);
    stats[(size_t)r0 + tid] = make_float2(mean, rstd);
  }
  if (w >= 2) {
    // ---- Kraw -> A (raw, swizzled); affine deferred to score phase ----
#pragma unroll
    for (int rb = 0; rb < 2; ++rb)
#pragma unroll
      for (int r = 0; r < 4; ++r) {
        int row = rb * 16 + g * 4 + r;
#pragma unroll
        for (int cb = 0; cb < 8; ++cb) {
          int kcol = (w - 2) * 128 + cb * 16 + c;
          A[row * 256 + (kcol ^ ((row & 7) * 8))] = f2bf(acc[rb][cb][r]);
        }
      }
  }
  __syncthreads();

  // ---- score phase: K = Kraw*rstd + affine(col,row) -> RoPE -> l2norm -> dots ----
  {
    int h = tid >> 5, row = tid & 31;
    float2 st = ST[row];
    float is = st.y, mis = st.x * st.y;
    const float2* tgp = trig + (size_t)(n0 + row) * 16;
    float ssq = 0.f, d0 = 0.f, d1 = 0.f;
#pragma unroll
    for (int j = 0; j < 4; ++j) {
      int u = h * 4 + j;
      s16x8 kvv = *(const s16x8*)&A[row * 256 + ((u ^ (row & 7)) * 8)];
      float2 t0 = tgp[j * 4 + 0], t1 = tgp[j * 4 + 1], t2 = tgp[j * 4 + 2], t3 = tgp[j * 4 + 3];
      float2 tg4[4] = {t0, t1, t2, t3};
#pragma unroll
      for (int t = 0; t < 4; ++t) {
        int col = h * 32 + j * 8 + 2 * t;
        float base0 = fmaf(CV0[col], is, fmaf(-mis, CV1[col], CV2[col]));
        float base1 = fmaf(CV0[col + 1], is, fmaf(-mis, CV1[col + 1], CV2[col + 1]));
        float k0 = fmaf(bf2f((unsigned short)kvv[2 * t]), is, base0);
        float k1 = fmaf(bf2f((unsigned short)kvv[2 * t + 1]), is, base1);
        float2 cs = tg4[t];
        float rv0 = k0 * cs.x - k1 * cs.y;
        float rv1 = fmaf(k1, cs.x, k0 * cs.y);
        ssq = fmaf(rv0, rv0, fmaf(rv1, rv1, ssq));
        d0 = fmaf(rv0, QH[col], fmaf(rv1, QH[col + 1], d0));
        d1 = fmaf(rv0, QH[256 + col], fmaf(rv1, QH[256 + col + 1], d1));
      }
    }
    float isv = 0.17677669529663687f / fmaxf(sqrtf(ssq), 1e-12f);
    scores[(size_t)((b * 8 + h) * 2 + 0) * 4096 + n0 + row] = d0 * isv;
    scores[(size_t)((b * 8 + h) * 2 + 1) * 4096 + n0 + row] = d1 * isv;
  }
}

// ---------------- wgt: stats -> tanh rescale -> softmax -> w~ = w*rstd, scalars S1,S2 ----------------
__global__ __launch_bounds__(256) void wgt_kernel(
    const float* __restrict__ scores, const float2* __restrict__ stats,
    float* __restrict__ wbuf, float2* __restrict__ sbuf) {
  int b = blockIdx.x >> 3, h = blockIdx.x & 7;
  const float* s0p = scores + (size_t)((b * 8 + h) * 2 + 0) * 4096;
  const float* s1p = scores + (size_t)((b * 8 + h) * 2 + 1) * 4096;
  float sa[16], sb[16];
  float a1 = 0.f, a2 = 0.f, b1 = 0.f, b2 = 0.f;
#pragma unroll
  for (int i = 0; i < 16; ++i) {
    int k = i * 256 + TID;
    sa[i] = s0p[k]; sb[i] = s1p[k];
    a1 += sa[i]; a2 += sa[i] * sa[i];
    b1 += sb[i]; b2 += sb[i] * sb[i];
  }
  __shared__ float red[16];
  int w = TID >> 6;
#pragma unroll
  for (int m = 1; m < 64; m <<= 1) {
    a1 += __shfl_xor(a1, m, 64); a2 += __shfl_xor(a2, m, 64);
    b1 += __shfl_xor(b1, m, 64); b2 += __shfl_xor(b2, m, 64);
  }
  if ((TID & 63) == 0) { red[w * 4] = a1; red[w * 4 + 1] = a2; red[w * 4 + 2] = b1; red[w * 4 + 3] = b2; }
  __syncthreads();
  a1 = red[0] + red[4] + red[8] + red[12];
  a2 = red[1] + red[5] + red[9] + red[13];
  b1 = red[2] + red[6] + red[10] + red[14];
  b2 = red[3] + red[7] + red[11] + red[15];
  float va = (a2 - a1 * a1 * (1.f / 4096.f)) * (1.f / 4095.f);   // ddof=1
  float vb = (b2 - b1 * b1 * (1.f / 4096.f)) * (1.f / 4095.f);
  float sga = fmaxf(sqrtf(fmaxf(va, 0.f)), 1e-3f);
  float sgb = fmaxf(sqrtf(fmaxf(vb, 0.f)), 1e-3f);
  float ia = 0.5f / sga, ib = 0.5f / sgb;
  float fa = 5.f * sga, fb = 5.f * sgb;
  float ea = 0.f, eb = 0.f;
#pragma unroll
  for (int i = 0; i < 16; ++i) {
    sa[i] = __expf(tanhf(sa[i] * ia) * fa);    // |arg| <= 5*sigma: no max-sub needed
    sb[i] = __expf(tanhf(sb[i] * ib) * fb);
    ea += sa[i]; eb += sb[i];
  }
#pragma unroll
  for (int m = 1; m < 64; m <<= 1) { ea += __shfl_xor(ea, m, 64); eb += __shfl_xor(eb, m, 64); }
  __syncthreads();
  if ((TID & 63) == 0) { red[w * 2] = ea; red[w * 2 + 1] = eb; }
  __syncthreads();
  ea = red[0] + red[2] + red[4] + red[6];
  eb = red[1] + red[3] + red[5] + red[7];
  float iea = 1.f / ea, ieb = 1.f / eb;   // denom (1+1e-8) == 1.0f in fp32
  float* w0 = wbuf + ((size_t)(b * 16) + h * 2 + 0) * 4096;
  float* w1 = w0 + 4096;
  float s1a = 0.f, s2a = 0.f, s1b = 0.f, s2b = 0.f;
#pragma unroll
  for (int i = 0; i < 16; ++i) {
    int k = i * 256 + TID;
    float2 st = stats[(size_t)b * 4096 + k];
    float wa = fmaf(sa[i], iea, 1e-4f);
    float wb = fmaf(sb[i], ieb, 1e-4f);
    float wta = wa * st.y, wtb = wb * st.y;
    w0[k] = wta; w1[k] = wtb;
    s1a += wta; s2a = fmaf(wta, st.x, s2a);
    s1b += wtb; s2b = fmaf(wtb, st.x, s2b);
  }
#pragma unroll
  for (int m = 1; m < 64; m <<= 1) {
    s1a += __shfl_xor(s1a, m, 64); s2a += __shfl_xor(s2a, m, 64);
    s1b += __shfl_xor(s1b, m, 64); s2b += __shfl_xor(s2b, m, 64);
  }
  __syncthreads();
  if ((TID & 63) == 0) { red[w * 4] = s1a; red[w * 4 + 1] = s2a; red[w * 4 + 2] = s1b; red[w * 4 + 3] = s2b; }
  __syncthreads();
  if (TID == 0) {
    sbuf[((size_t)(b * 8 + h)) * 2 + 0] =
        make_float2(red[0] + red[4] + red[8] + red[12], red[1] + red[5] + red[9] + red[13]);
    sbuf[((size_t)(b * 8 + h)) * 2 + 1] =
        make_float2(red[2] + red[6] + red[10] + red[14], red[3] + red[7] + red[11] + red[15]);
  }
}

// ---------------- ysum: yin partials = sum_n w~[n] * X_in[n,:] (fp32 input, exact) ----------------
__global__ __launch_bounds__(256) void ysum_kernel(
    const float* __restrict__ x, const float* __restrict__ wbuf,
    float* __restrict__ ypart) {
  int b = blockIdx.x >> 5, slab = blockIdx.x & 31;
  int h = TID >> 5, cg = TID & 31;                 // 8 heads x 32 col-groups
  const float* xb = x + ((size_t)(b * 4096 + slab * 128)) * 256 + cg * 8;
  const float* w0 = wbuf + ((size_t)(b * 16) + h * 2 + 0) * 4096 + slab * 128;
  const float* w1 = w0 + 4096;
  float y0[8], y1[8];
#pragma unroll
  for (int t = 0; t < 8; ++t) { y0[t] = 0.f; y1[t] = 0.f; }
#pragma unroll 4
  for (int r = 0; r < 128; ++r) {
    const float4* fp = (const float4*)(xb + (size_t)r * 256);
    float4 va = fp[0], vb4 = fp[1];
    float wa = w0[r], wc = w1[r];
    y0[0] = fmaf(wa, va.x, y0[0]);  y1[0] = fmaf(wc, va.x, y1[0]);
    y0[1] = fmaf(wa, va.y, y0[1]);  y1[1] = fmaf(wc, va.y, y1[1]);
    y0[2] = fmaf(wa, va.z, y0[2]);  y1[2] = fmaf(wc, va.z, y1[2]);
    y0[3] = fmaf(wa, va.w, y0[3]);  y1[3] = fmaf(wc, va.w, y1[3]);
    y0[4] = fmaf(wa, vb4.x, y0[4]); y1[4] = fmaf(wc, vb4.x, y1[4]);
    y0[5] = fmaf(wa, vb4.y, y0[5]); y1[5] = fmaf(wc, vb4.y, y1[5]);
    y0[6] = fmaf(wa, vb4.z, y0[6]); y1[6] = fmaf(wc, vb4.z, y1[6]);
    y0[7] = fmaf(wa, vb4.w, y0[7]); y1[7] = fmaf(wc, vb4.w, y1[7]);
  }
  float* yp = ypart + (((size_t)(b * 32 + slab) * 16) + h * 2) * 256 + cg * 8;
  *(float4*)&yp[0] = (float4){y0[0], y0[1], y0[2], y0[3]};
  *(float4*)&yp[4] = (float4){y0[4], y0[5], y0[6], y0[7]};
  *(float4*)&yp[256] = (float4){y1[0], y1[1], y1[2], y1[3]};
  *(float4*)&yp[260] = (float4){y1[4], y1[5], y1[6], y1[7]};
}

// ---------------- finish: reduce yin; z = (yin.We + S1.be - S2).g + 1.4096*bln; attn = z.Wv + 1.4096*vb ----------------
__global__ __launch_bounds__(256) void finish_kernel(
    const float* __restrict__ ypart, const float2* __restrict__ sbuf,
    const float* __restrict__ We, const float* __restrict__ be,
    const float* __restrict__ g, const float* __restrict__ bln,
    const float* __restrict__ v_w, const float* __restrict__ v_b,
    const float* __restrict__ fc_w, const float* __restrict__ fc_b,
    float* __restrict__ out_attn, float* __restrict__ out_pooled,
    float* __restrict__ out_logits) {
  int b = blockIdx.x;
  __shared__ float Y[16][256];
  __shared__ float Z[16][257];
  __shared__ float ATT[2][256];
  __shared__ float P[256];
  for (int idx = TID; idx < 4096; idx += 256) {
    int hq = idx >> 8, cc = idx & 255;
    float s = 0.f;
#pragma unroll 8
    for (int sl = 0; sl < 32; ++sl)
      s += ypart[(((size_t)(b * 32 + sl) * 16) + hq) * 256 + cc];
    Y[hq][cc] = s;
  }
  __syncthreads();
#pragma unroll
  for (int o4 = 0; o4 < 16; ++o4) {
    int hq = o4, k = TID;
    float2 s12 = sbuf[(size_t)b * 16 + hq];
    float t = s12.x * be[k];
#pragma unroll 8
    for (int cc = 0; cc < 256; ++cc)
      t = fmaf(Y[hq][cc], We[cc * 256 + k], t);
    Z[hq][k] = (t - s12.y) * g[k] + 1.4096f * bln[k];
  }
  __syncthreads();
#pragma unroll
  for (int o = TID; o < 512; o += 256) {
    int q = o >> 8, dout = o & 255;
    int hq = (dout >> 5) * 2 + q;
    float acc = 1.4096f * v_b[dout];
#pragma unroll 8
    for (int cc = 0; cc < 256; ++cc)
      acc = fmaf(Z[hq][cc], v_w[cc * 256 + dout], acc);
    out_attn[(b * 2 + q) * 256 + dout] = acc;
    ATT[q][dout] = acc;
  }
  __syncthreads();
  float p = 0.5f * (ATT[0][TID] + ATT[1][TID]);
  out_pooled[b * 256 + TID] = p;
  P[TID] = p;
  __syncthreads();
  if (TID < 40) {
    float acc = fc_b[TID];
#pragma unroll 8
    for (int i = 0; i < 256; ++i) acc = fmaf(P[i], fc_w[i * 40 + TID], acc);
    out_logits[b * 40 + TID] = acc;
  }
}

extern "C" void kernel_launch(void* const* d_in, const int* in_sizes, int n_in,
                              void* d_out, int out_size, void* d_ws, size_t ws_size,
                              hipStream_t stream) {
  (void)in_sizes; (void)n_in; (void)out_size; (void)ws_size;
  const float* eeg_feat  = (const float*)d_in[0];
  const float* stim_feat = (const float*)d_in[1];
  const float* temp_feat = (const float*)d_in[2];
  const float* eeg_w = (const float*)d_in[3];
  const float* eeg_b = (const float*)d_in[4];
  const float* stim_w = (const float*)d_in[5];
  const float* stim_b = (const float*)d_in[6];
  const float* temp_w = (const float*)d_in[7];
  const float* temp_b = (const float*)d_in[8];
  const float* q_w = (const float*)d_in[9];
  const float* q_b = (const float*)d_in[10];
  const float* k_w = (const float*)d_in[11];
  const float* k_b = (const float*)d_in[12];
  const float* v_w = (const float*)d_in[13];
  const float* v_b = (const float*)d_in[14];
  const float* fc_w = (const float*)d_in[15];
  const float* fc_b = (const float*)d_in[16];
  const float* lnq_g = (const float*)d_in[17];
  const float* lnq_b = (const float*)d_in[18];
  const float* lnk_g = (const float*)d_in[19];
  const float* lnk_b = (const float*)d_in[20];

  char* ws = (char*)d_ws;
  unsigned short* wfr = (unsigned short*)(ws + 0);          // 256 KB (fragment-order [We | Wck])
  float2* trig        = (float2*)(ws + 262144);             // 512 KB
  float* qhat         = (float*)(ws + 786432);              // 64 KB
  float* ckv          = (float*)(ws + 851968);              // 1 KB
  float* gkv          = (float*)(ws + 852992);              // 1 KB
  float* bkv          = (float*)(ws + 854016);              // 1 KB
  float2* sbuf        = (float2*)(ws + 855040);             // 4 KB
  float2* stats       = (float2*)(ws + 1048576);            // 1 MB
  float* scores       = (float*)(ws + 2097152);             // 8 MB
  float* wbuf         = (float*)(ws + 10485760);            // 8 MB
  float* ypart        = (float*)(ws + 18874368);            // 16 MB

  float* out = (float*)d_out;
  float* out_logits = out;                 // 32*40
  float* out_pooled = out + 1280;          // 32*256
  float* out_attn   = out + 9472;          // 32*2*256
  float* out_query  = out + 25856;         // 32*2*256

  prep1_kernel<<<289, 256, 0, stream>>>(eeg_w, k_w, lnk_g, eeg_b, lnk_b, k_b,
                                        wfr, trig, ckv, gkv, bkv);
  prep2_kernel<<<256, 256, 0, stream>>>(eeg_w, k_w, lnk_g, wfr);
  q_kernel<<<64, 256, 0, stream>>>(stim_feat, temp_feat, stim_w, stim_b,
                                   temp_w, temp_b, q_w, q_b, lnq_g, lnq_b,
                                   out_query, qhat);
  main2_kernel<<<4096, 256, 0, stream>>>(eeg_feat, eeg_b, wfr, trig, qhat,
                                         ckv, gkv, bkv, stats, scores);
  wgt_kernel<<<256, 256, 0, stream>>>(scores, stats, wbuf, sbuf);
  ysum_kernel<<<1024, 256, 0, stream>>>(eeg_feat, wbuf, ypart);
  finish_kernel<<<32, 256, 0, stream>>>(ypart, sbuf, eeg_w, eeg_b, lnk_g, lnk_b,
                                        v_w, v_b, fc_w, fc_b,
                                        out_attn, out_pooled, out_logits);
}

// Round 9
// 216.502 us; speedup vs baseline: 1.7267x; 1.4135x over previous
//
#include <hip/hip_runtime.h>
#include <hip/hip_bf16.h>
#include <math.h>

#define TID ((int)threadIdx.x)

typedef float f32x4 __attribute__((ext_vector_type(4)));
typedef short s16x8 __attribute__((ext_vector_type(8)));

__device__ __forceinline__ unsigned short f2bf(float f) {
  union { float f; unsigned u; } v; v.f = f;
  unsigned r = v.u + 0x7FFFu + ((v.u >> 16) & 1u);
  return (unsigned short)(r >> 16);
}
__device__ __forceinline__ float bf2f(unsigned short h) {
  union { unsigned u; float f; } v; v.u = ((unsigned)h) << 16;
  return v.f;
}

// ---------------- prep1: We -> wf fragment layout, trig table, K-path vectors ----------------
// wf fragment layout: wf[((cbG*8 + ks)*64 + lane)*8 + e] = W[k][col],
//   col = cbG*16 + (lane&15), k = ks*32 + (lane>>4)*8 + e.  cbG 0..15 = We, 16..31 = Wck.
__global__ __launch_bounds__(256) void prep1_kernel(
    const float* __restrict__ We, const float* __restrict__ Wk,
    const float* __restrict__ g, const float* __restrict__ be,
    const float* __restrict__ bln, const float* __restrict__ kb,
    unsigned short* __restrict__ wf, float2* __restrict__ trig,
    float* __restrict__ ckv, float* __restrict__ gkv, float* __restrict__ bkv) {
  int blk = blockIdx.x;
  if (blk < 32) {                        // We -> fragment layout (cbG 0..15)
    int fi = blk * 256 + TID;            // [0, 8192)
    int l = fi & 63, ks = (fi >> 6) & 7, cbG = fi >> 9;
    int col = cbG * 16 + (l & 15);
    int kbase = ks * 32 + ((l >> 4) & 3) * 8;
    s16x8 pk;
#pragma unroll
    for (int e = 0; e < 8; ++e) pk[e] = (short)f2bf(We[(size_t)(kbase + e) * 256 + col]);
    *(s16x8*)&wf[(size_t)fi * 8] = pk;
  } else if (blk < 288) {                // trig
    int e = (blk - 32) * 256 + TID;      // < 65536 = 4096*16
    int n = e >> 4, p = e & 15;
    float inv = exp2f(-(float)p * 0.8304820237218406f);  // 10000^(-p/16)
    float a = (float)n * inv;
    trig[e] = make_float2(cosf(a), sinf(a));
  } else {                               // vectors (one block)
    int j = TID;
    float a1 = 0.f, a2 = 0.f, a3 = 0.f;
    for (int k = 0; k < 256; ++k) {
      float wkj = Wk[k * 256 + j];       // coalesced across j lanes
      float gk = g[k];
      a1 = fmaf(be[k] * gk, wkj, a1);
      a2 = fmaf(gk, wkj, a2);
      a3 = fmaf(bln[k], wkj, a3);
    }
    ckv[j] = a1; gkv[j] = a2; bkv[j] = a3 + kb[j];
  }
}

// ---------------- prep2: Wck = We . diag(g) . Wk (fp32) -> wf fragment layout (cbG 16..31) ----------------
__global__ __launch_bounds__(256) void prep2_kernel(
    const float* __restrict__ We, const float* __restrict__ Wk,
    const float* __restrict__ g, unsigned short* __restrict__ wf) {
  int j = blockIdx.x;                    // output col of Wck
  __shared__ float a[256];
  __shared__ float WeC[256 * 33];
  a[TID] = g[TID] * Wk[TID * 256 + j];
  float acc = 0.f;
  for (int k0 = 0; k0 < 256; k0 += 32) {
    __syncthreads();
    const float4* src = (const float4*)&We[TID * 256 + k0];
#pragma unroll
    for (int q4 = 0; q4 < 8; ++q4) {
      float4 v = src[q4];
      WeC[TID * 33 + q4 * 4 + 0] = v.x;
      WeC[TID * 33 + q4 * 4 + 1] = v.y;
      WeC[TID * 33 + q4 * 4 + 2] = v.z;
      WeC[TID * 33 + q4 * 4 + 3] = v.w;
    }
    __syncthreads();
#pragma unroll
    for (int kk = 0; kk < 32; ++kk)
      acc = fmaf(WeC[TID * 33 + kk], a[k0 + kk], acc);
  }
  int cbG = 16 + (j >> 4), c = j & 15;
  int ks = TID >> 5, g3 = (TID >> 3) & 3, e = TID & 7;
  size_t pos = (((size_t)(cbG * 8 + ks) * 64) + g3 * 16 + c) * 8 + e;
  wf[pos] = f2bf(acc);
}

// ---------------- query path (unchanged, verified) ----------------
__global__ __launch_bounds__(256) void q_kernel(
    const float* __restrict__ stim_feat, const float* __restrict__ temp_feat,
    const float* __restrict__ stim_w, const float* __restrict__ stim_b,
    const float* __restrict__ temp_w, const float* __restrict__ temp_b,
    const float* __restrict__ q_w, const float* __restrict__ q_b,
    const float* __restrict__ lnq_g, const float* __restrict__ lnq_b,
    float* __restrict__ out_query, float* __restrict__ qhat) {
  int b = blockIdx.x >> 1, q = blockIdx.x & 1;
  __shared__ float f[256];
  __shared__ float red[8];
  const float* feat = (q ? temp_feat : stim_feat) + b * 256;
  const float* W = q ? temp_w : stim_w;
  const float* bias = q ? temp_b : stim_b;
  f[TID] = feat[TID];
  __syncthreads();
  float acc = bias[TID];
#pragma unroll 8
  for (int i = 0; i < 256; ++i) acc = fmaf(f[i], W[i * 256 + TID], acc);
  float s1 = acc, s2 = acc * acc;
#pragma unroll
  for (int m = 1; m < 64; m <<= 1) { s1 += __shfl_xor(s1, m, 64); s2 += __shfl_xor(s2, m, 64); }
  if ((TID & 63) == 0) { red[TID >> 6] = s1; red[4 + (TID >> 6)] = s2; }
  __syncthreads();
  s1 = red[0] + red[1] + red[2] + red[3];
  s2 = red[4] + red[5] + red[6] + red[7];
  float mean = s1 * (1.f / 256.f);
  float var = s2 * (1.f / 256.f) - mean * mean;
  float rstd = rsqrtf(var + 1e-5f);
  float qln = (acc - mean) * rstd * lnq_g[TID] + lnq_b[TID];
  out_query[(b * 2 + q) * 256 + TID] = qln;
  __syncthreads();
  f[TID] = qln;
  __syncthreads();
  float a2 = q_b[TID];
#pragma unroll 8
  for (int i = 0; i < 256; ++i) a2 = fmaf(f[i], q_w[i * 256 + TID], a2);
  __syncthreads();
  f[TID] = a2;
  __syncthreads();
  float partner = f[TID ^ 1];
  int p = (TID >> 1) & 15;
  float inv = exp2f(-(float)p * 0.8304820237218406f);
  float ang = (float)q * inv;
  float cc_ = cosf(ang), ss_ = sinf(ang);
  float r = (TID & 1) ? fmaf(a2, cc_, partner * ss_) : fmaf(a2, cc_, -partner * ss_);
  float sq = r * r;
#pragma unroll
  for (int m = 1; m < 32; m <<= 1) sq += __shfl_xor(sq, m, 32);
  float rs = 1.f / fmaxf(sqrtf(sq), 1e-12f);
  qhat[(b * 2 + q) * 256 + TID] = r * rs;
}

// ---------------- main2: one 512-col GEMM [E | Kraw] -> stats + scores (coalesced B) ----------------
__global__ __launch_bounds__(256) void main2_kernel(
    const float* __restrict__ x,
    const float* __restrict__ eeg_b,
    const unsigned short* __restrict__ wf,
    const float2* __restrict__ trig,
    const float* __restrict__ qhat,
    const float* __restrict__ ckv,
    const float* __restrict__ gkv,
    const float* __restrict__ bkv,
    float2* __restrict__ stats,
    float* __restrict__ scores) {

  __shared__ __align__(16) unsigned short A[32 * 256];  // 16KB: X tile, then Kraw (both swizzled)
  __shared__ float CV0[256];
  __shared__ float CV1[256];
  __shared__ float CV2[256];
  __shared__ float QH[512];
  __shared__ float PS[32 * 9];
  __shared__ float2 ST[32];

  const int tid = TID;
  const int w = tid >> 6, l = tid & 63, g = l >> 4, c = l & 15;
  const int r0 = blockIdx.x * 32;
  const int b = r0 >> 12;
  const int n0 = r0 & 4095;

  // ---- stage X (fp32 -> bf16, swizzled) + CV + QH ----
#pragma unroll
  for (int i = 0; i < 4; ++i) {
    int ch = i * 256 + tid;
    int row = ch >> 5, cc = ch & 31;
    const float4* gp = (const float4*)(x + (size_t)(r0 + row) * 256 + cc * 8);
    float4 u0 = gp[0], u1 = gp[1];
    s16x8 pk;
    pk[0] = (short)f2bf(u0.x); pk[1] = (short)f2bf(u0.y);
    pk[2] = (short)f2bf(u0.z); pk[3] = (short)f2bf(u0.w);
    pk[4] = (short)f2bf(u1.x); pk[5] = (short)f2bf(u1.y);
    pk[6] = (short)f2bf(u1.z); pk[7] = (short)f2bf(u1.w);
    *(s16x8*)&A[row * 256 + ((cc ^ (row & 7)) * 8)] = pk;
  }
  CV0[tid] = ckv[tid]; CV1[tid] = gkv[tid]; CV2[tid] = bkv[tid];
  QH[tid] = qhat[(size_t)b * 512 + tid];
  QH[256 + tid] = qhat[(size_t)b * 512 + 256 + tid];
  __syncthreads();

  // ---- combined GEMM: wave w owns cols [w*128, w*128+128) of [We | Wck] ----
  f32x4 acc[2][8];
#pragma unroll
  for (int rb = 0; rb < 2; ++rb)
#pragma unroll
    for (int cb = 0; cb < 8; ++cb) acc[rb][cb] = (f32x4){0.f, 0.f, 0.f, 0.f};
#pragma unroll
  for (int ks = 0; ks < 8; ++ks) {
    s16x8 af[2];
#pragma unroll
    for (int rb = 0; rb < 2; ++rb) {
      int row = rb * 16 + c; int kc = ks * 4 + g;
      af[rb] = *(const s16x8*)&A[row * 256 + ((kc ^ (row & 7)) * 8)];
    }
#pragma unroll
    for (int hb = 0; hb < 2; ++hb) {
      s16x8 bf4[4];
#pragma unroll
      for (int q4 = 0; q4 < 4; ++q4) {
        int cbG = w * 8 + hb * 4 + q4;
        bf4[q4] = *(const s16x8*)&wf[(size_t)((cbG * 8 + ks) * 64 + l) * 8];  // 1KB contiguous/wave
      }
#pragma unroll
      for (int rb = 0; rb < 2; ++rb)
#pragma unroll
        for (int q4 = 0; q4 < 4; ++q4)
          acc[rb][hb * 4 + q4] = __builtin_amdgcn_mfma_f32_16x16x32_bf16(
              af[rb], bf4[q4], acc[rb][hb * 4 + q4], 0, 0, 0);
    }
  }

  // ---- LN stats over the E half (waves 0,1) ----
  if (w < 2) {
    float ebias[8];
#pragma unroll
    for (int cb = 0; cb < 8; ++cb) ebias[cb] = eeg_b[w * 128 + cb * 16 + c];
    float ps[2][4], pq[2][4];
#pragma unroll
    for (int rb = 0; rb < 2; ++rb)
#pragma unroll
      for (int r = 0; r < 4; ++r) {
        float s = 0.f, q2 = 0.f;
#pragma unroll
        for (int cb = 0; cb < 8; ++cb) {
          float v = acc[rb][cb][r] + ebias[cb];
          s += v; q2 += v * v;
        }
        ps[rb][r] = s; pq[rb][r] = q2;
      }
#pragma unroll
    for (int m = 1; m < 16; m <<= 1)
#pragma unroll
      for (int rb = 0; rb < 2; ++rb)
#pragma unroll
        for (int r = 0; r < 4; ++r) {
          ps[rb][r] += __shfl_xor(ps[rb][r], m, 64);
          pq[rb][r] += __shfl_xor(pq[rb][r], m, 64);
        }
    float outS = 0.f, outQ = 0.f;
#pragma unroll
    for (int rb = 0; rb < 2; ++rb)
#pragma unroll
      for (int r = 0; r < 4; ++r)
        if (c == rb * 4 + r) { outS = ps[rb][r]; outQ = pq[rb][r]; }
    if (c < 8) {
      int row = (c >> 2) * 16 + g * 4 + (c & 3);
      PS[row * 9 + w * 2 + 0] = outS;
      PS[row * 9 + w * 2 + 1] = outQ;
    }
  }
  __syncthreads();   // all GEMM A-reads done; PS complete

  if (tid < 32) {
    float s = PS[tid * 9 + 0] + PS[tid * 9 + 2];
    float q2 = PS[tid * 9 + 1] + PS[tid * 9 + 3];
    float mean = s * (1.f / 256.f);
    float var = q2 * (1.f / 256.f) - mean * mean;
    float rstd = rsqrtf(var + 1e-5f);
    ST[tid] = make_float2(mean, rstd);
    stats[(size_t)r0 + tid] = make_float2(mean, rstd);
  }
  if (w >= 2) {
    // ---- Kraw -> A (raw, swizzled); affine deferred to score phase ----
#pragma unroll
    for (int rb = 0; rb < 2; ++rb)
#pragma unroll
      for (int r = 0; r < 4; ++r) {
        int row = rb * 16 + g * 4 + r;
#pragma unroll
        for (int cb = 0; cb < 8; ++cb) {
          int kcol = (w - 2) * 128 + cb * 16 + c;
          A[row * 256 + (kcol ^ ((row & 7) * 8))] = f2bf(acc[rb][cb][r]);
        }
      }
  }
  __syncthreads();

  // ---- score phase: K = Kraw*rstd + affine(col,row) -> RoPE -> l2norm -> dots ----
  {
    int h = tid >> 5, row = tid & 31;
    float2 st = ST[row];
    float is = st.y, mis = st.x * st.y;
    const float2* tgp = trig + (size_t)(n0 + row) * 16;
    float ssq = 0.f, d0 = 0.f, d1 = 0.f;
#pragma unroll
    for (int j = 0; j < 4; ++j) {
      int u = h * 4 + j;
      s16x8 kvv = *(const s16x8*)&A[row * 256 + ((u ^ (row & 7)) * 8)];
      float2 t0 = tgp[j * 4 + 0], t1 = tgp[j * 4 + 1], t2 = tgp[j * 4 + 2], t3 = tgp[j * 4 + 3];
      float2 tg4[4] = {t0, t1, t2, t3};
#pragma unroll
      for (int t = 0; t < 4; ++t) {
        int col = h * 32 + j * 8 + 2 * t;
        float base0 = fmaf(CV0[col], is, fmaf(-mis, CV1[col], CV2[col]));
        float base1 = fmaf(CV0[col + 1], is, fmaf(-mis, CV1[col + 1], CV2[col + 1]));
        float k0 = fmaf(bf2f((unsigned short)kvv[2 * t]), is, base0);
        float k1 = fmaf(bf2f((unsigned short)kvv[2 * t + 1]), is, base1);
        float2 cs = tg4[t];
        float rv0 = k0 * cs.x - k1 * cs.y;
        float rv1 = fmaf(k1, cs.x, k0 * cs.y);
        ssq = fmaf(rv0, rv0, fmaf(rv1, rv1, ssq));
        d0 = fmaf(rv0, QH[col], fmaf(rv1, QH[col + 1], d0));
        d1 = fmaf(rv0, QH[256 + col], fmaf(rv1, QH[256 + col + 1], d1));
      }
    }
    float isv = 0.17677669529663687f / fmaxf(sqrtf(ssq), 1e-12f);
    scores[(size_t)((b * 8 + h) * 2 + 0) * 4096 + n0 + row] = d0 * isv;
    scores[(size_t)((b * 8 + h) * 2 + 1) * 4096 + n0 + row] = d1 * isv;
  }
}

// ---------------- wgt: stats -> tanh rescale -> softmax -> w~ = w*rstd, scalars S1,S2 ----------------
__global__ __launch_bounds__(256) void wgt_kernel(
    const float* __restrict__ scores, const float2* __restrict__ stats,
    float* __restrict__ wbuf, float2* __restrict__ sbuf) {
  int b = blockIdx.x >> 3, h = blockIdx.x & 7;
  const float* s0p = scores + (size_t)((b * 8 + h) * 2 + 0) * 4096;
  const float* s1p = scores + (size_t)((b * 8 + h) * 2 + 1) * 4096;
  float sa[16], sb[16];
  float a1 = 0.f, a2 = 0.f, b1 = 0.f, b2 = 0.f;
#pragma unroll
  for (int i = 0; i < 16; ++i) {
    int k = i * 256 + TID;
    sa[i] = s0p[k]; sb[i] = s1p[k];
    a1 += sa[i]; a2 += sa[i] * sa[i];
    b1 += sb[i]; b2 += sb[i] * sb[i];
  }
  __shared__ float red[16];
  int w = TID >> 6;
#pragma unroll
  for (int m = 1; m < 64; m <<= 1) {
    a1 += __shfl_xor(a1, m, 64); a2 += __shfl_xor(a2, m, 64);
    b1 += __shfl_xor(b1, m, 64); b2 += __shfl_xor(b2, m, 64);
  }
  if ((TID & 63) == 0) { red[w * 4] = a1; red[w * 4 + 1] = a2; red[w * 4 + 2] = b1; red[w * 4 + 3] = b2; }
  __syncthreads();
  a1 = red[0] + red[4] + red[8] + red[12];
  a2 = red[1] + red[5] + red[9] + red[13];
  b1 = red[2] + red[6] + red[10] + red[14];
  b2 = red[3] + red[7] + red[11] + red[15];
  float va = (a2 - a1 * a1 * (1.f / 4096.f)) * (1.f / 4095.f);   // ddof=1
  float vb = (b2 - b1 * b1 * (1.f / 4096.f)) * (1.f / 4095.f);
  float sga = fmaxf(sqrtf(fmaxf(va, 0.f)), 1e-3f);
  float sgb = fmaxf(sqrtf(fmaxf(vb, 0.f)), 1e-3f);
  float ia = 0.5f / sga, ib = 0.5f / sgb;
  float fa = 5.f * sga, fb = 5.f * sgb;
  float ea = 0.f, eb = 0.f;
#pragma unroll
  for (int i = 0; i < 16; ++i) {
    sa[i] = __expf(tanhf(sa[i] * ia) * fa);    // |arg| <= 5*sigma: no max-sub needed
    sb[i] = __expf(tanhf(sb[i] * ib) * fb);
    ea += sa[i]; eb += sb[i];
  }
#pragma unroll
  for (int m = 1; m < 64; m <<= 1) { ea += __shfl_xor(ea, m, 64); eb += __shfl_xor(eb, m, 64); }
  __syncthreads();
  if ((TID & 63) == 0) { red[w * 2] = ea; red[w * 2 + 1] = eb; }
  __syncthreads();
  ea = red[0] + red[2] + red[4] + red[6];
  eb = red[1] + red[3] + red[5] + red[7];
  float iea = 1.f / ea, ieb = 1.f / eb;   // denom (1+1e-8) == 1.0f in fp32
  float* w0 = wbuf + ((size_t)(b * 16) + h * 2 + 0) * 4096;
  float* w1 = w0 + 4096;
  float s1a = 0.f, s2a = 0.f, s1b = 0.f, s2b = 0.f;
#pragma unroll
  for (int i = 0; i < 16; ++i) {
    int k = i * 256 + TID;
    float2 st = stats[(size_t)b * 4096 + k];
    float wa = fmaf(sa[i], iea, 1e-4f);
    float wb = fmaf(sb[i], ieb, 1e-4f);
    float wta = wa * st.y, wtb = wb * st.y;
    w0[k] = wta; w1[k] = wtb;
    s1a += wta; s2a = fmaf(wta, st.x, s2a);
    s1b += wtb; s2b = fmaf(wtb, st.x, s2b);
  }
#pragma unroll
  for (int m = 1; m < 64; m <<= 1) {
    s1a += __shfl_xor(s1a, m, 64); s2a += __shfl_xor(s2a, m, 64);
    s1b += __shfl_xor(s1b, m, 64); s2b += __shfl_xor(s2b, m, 64);
  }
  __syncthreads();
  if ((TID & 63) == 0) { red[w * 4] = s1a; red[w * 4 + 1] = s2a; red[w * 4 + 2] = s1b; red[w * 4 + 3] = s2b; }
  __syncthreads();
  if (TID == 0) {
    sbuf[((size_t)(b * 8 + h)) * 2 + 0] =
        make_float2(red[0] + red[4] + red[8] + red[12], red[1] + red[5] + red[9] + red[13]);
    sbuf[((size_t)(b * 8 + h)) * 2 + 1] =
        make_float2(red[2] + red[6] + red[10] + red[14], red[3] + red[7] + red[11] + red[15]);
  }
}

// ---------------- ysum: yin partials = sum_n w~[n] * X_in[n,:] (fp32 input, exact) ----------------
__global__ __launch_bounds__(256) void ysum_kernel(
    const float* __restrict__ x, const float* __restrict__ wbuf,
    float* __restrict__ ypart) {
  int b = blockIdx.x >> 5, slab = blockIdx.x & 31;
  int h = TID >> 5, cg = TID & 31;                 // 8 heads x 32 col-groups
  const float* xb = x + ((size_t)(b * 4096 + slab * 128)) * 256 + cg * 8;
  const float* w0 = wbuf + ((size_t)(b * 16) + h * 2 + 0) * 4096 + slab * 128;
  const float* w1 = w0 + 4096;
  float y0[8], y1[8];
#pragma unroll
  for (int t = 0; t < 8; ++t) { y0[t] = 0.f; y1[t] = 0.f; }
#pragma unroll 4
  for (int r = 0; r < 128; ++r) {
    const float4* fp = (const float4*)(xb + (size_t)r * 256);
    float4 va = fp[0], vb4 = fp[1];
    float wa = w0[r], wc = w1[r];
    y0[0] = fmaf(wa, va.x, y0[0]);  y1[0] = fmaf(wc, va.x, y1[0]);
    y0[1] = fmaf(wa, va.y, y0[1]);  y1[1] = fmaf(wc, va.y, y1[1]);
    y0[2] = fmaf(wa, va.z, y0[2]);  y1[2] = fmaf(wc, va.z, y1[2]);
    y0[3] = fmaf(wa, va.w, y0[3]);  y1[3] = fmaf(wc, va.w, y1[3]);
    y0[4] = fmaf(wa, vb4.x, y0[4]); y1[4] = fmaf(wc, vb4.x, y1[4]);
    y0[5] = fmaf(wa, vb4.y, y0[5]); y1[5] = fmaf(wc, vb4.y, y1[5]);
    y0[6] = fmaf(wa, vb4.z, y0[6]); y1[6] = fmaf(wc, vb4.z, y1[6]);
    y0[7] = fmaf(wa, vb4.w, y0[7]); y1[7] = fmaf(wc, vb4.w, y1[7]);
  }
  float* yp = ypart + (((size_t)(b * 32 + slab) * 16) + h * 2) * 256 + cg * 8;
  *(float4*)&yp[0] = (float4){y0[0], y0[1], y0[2], y0[3]};
  *(float4*)&yp[4] = (float4){y0[4], y0[5], y0[6], y0[7]};
  *(float4*)&yp[256] = (float4){y1[0], y1[1], y1[2], y1[3]};
  *(float4*)&yp[260] = (float4){y1[4], y1[5], y1[6], y1[7]};
}

// ---------------- yz: (b,hq) block: Y = reduce(ypart); Z[k] = (Y.We[:,k] + S1*be[k] - S2)*g[k] + 1.4096*bln[k] ----------------
__global__ __launch_bounds__(256) void yz_kernel(
    const float* __restrict__ ypart, const float2* __restrict__ sbuf,
    const float* __restrict__ We, const float* __restrict__ be,
    const float* __restrict__ g, const float* __restrict__ bln,
    float* __restrict__ zbuf) {
  int b = blockIdx.x >> 4, hq = blockIdx.x & 15;
  __shared__ float Y[256];
  float s = 0.f;
#pragma unroll 8
  for (int sl = 0; sl < 32; ++sl)
    s += ypart[(((size_t)(b * 32 + sl) * 16) + hq) * 256 + TID];
  Y[TID] = s;
  __syncthreads();
  float2 s12 = sbuf[(size_t)b * 16 + hq];
  int k = TID;
  float t = s12.x * be[k];
#pragma unroll 8
  for (int cc = 0; cc < 256; ++cc)
    t = fmaf(Y[cc], We[cc * 256 + k], t);
  zbuf[((size_t)(b * 16) + hq) * 256 + k] = (t - s12.y) * g[k] + 1.4096f * bln[k];
}

// ---------------- att: (b,h) block: ATT[q][dout] = Z[hq] . Wv[:,dout] + 1.4096*vb; pooled ----------------
__global__ __launch_bounds__(256) void att_kernel(
    const float* __restrict__ zbuf, const float* __restrict__ v_w,
    const float* __restrict__ v_b, float* __restrict__ out_attn,
    float* __restrict__ out_pooled) {
  int b = blockIdx.x >> 3, h = blockIdx.x & 7;
  __shared__ float ZA[2][256];
  __shared__ float ATTs[2][32];
  {
    int q = TID >> 7, cc = TID & 127;
    const float* zp = zbuf + ((size_t)(b * 16) + h * 2 + q) * 256;
    ZA[q][cc] = zp[cc];
    ZA[q][128 + cc] = zp[128 + cc];
  }
  __syncthreads();
  // thread t = q*128 + dl*4 + quarter
  int q = TID >> 7, dl = (TID >> 2) & 31, quarter = TID & 3;
  int dout = h * 32 + dl;
  float ps = 0.f;
#pragma unroll 8
  for (int i = 0; i < 64; ++i) {
    int cc = quarter * 64 + i;
    ps = fmaf(ZA[q][cc], v_w[cc * 256 + dout], ps);
  }
  ps += __shfl_xor(ps, 1, 64);
  ps += __shfl_xor(ps, 2, 64);
  if (quarter == 0) {
    float val = ps + 1.4096f * v_b[dout];
    out_attn[(b * 2 + q) * 256 + dout] = val;
    ATTs[q][dl] = val;
  }
  __syncthreads();
  if (TID < 32) {
    out_pooled[b * 256 + h * 32 + TID] = 0.5f * (ATTs[0][TID] + ATTs[1][TID]);
  }
}

// ---------------- logit: pooled @ fc_w + fc_b ----------------
__global__ __launch_bounds__(256) void logit_kernel(
    const float* __restrict__ out_pooled, const float* __restrict__ fc_w,
    const float* __restrict__ fc_b, float* __restrict__ out_logits) {
  int b = blockIdx.x;
  __shared__ float P[256];
  P[TID] = out_pooled[b * 256 + TID];
  __syncthreads();
  if (TID < 40) {
    float acc = fc_b[TID];
#pragma unroll 8
    for (int i = 0; i < 256; ++i) acc = fmaf(P[i], fc_w[i * 40 + TID], acc);
    out_logits[b * 40 + TID] = acc;
  }
}

extern "C" void kernel_launch(void* const* d_in, const int* in_sizes, int n_in,
                              void* d_out, int out_size, void* d_ws, size_t ws_size,
                              hipStream_t stream) {
  (void)in_sizes; (void)n_in; (void)out_size; (void)ws_size;
  const float* eeg_feat  = (const float*)d_in[0];
  const float* stim_feat = (const float*)d_in[1];
  const float* temp_feat = (const float*)d_in[2];
  const float* eeg_w = (const float*)d_in[3];
  const float* eeg_b = (const float*)d_in[4];
  const float* stim_w = (const float*)d_in[5];
  const float* stim_b = (const float*)d_in[6];
  const float* temp_w = (const float*)d_in[7];
  const float* temp_b = (const float*)d_in[8];
  const float* q_w = (const float*)d_in[9];
  const float* q_b = (const float*)d_in[10];
  const float* k_w = (const float*)d_in[11];
  const float* k_b = (const float*)d_in[12];
  const float* v_w = (const float*)d_in[13];
  const float* v_b = (const float*)d_in[14];
  const float* fc_w = (const float*)d_in[15];
  const float* fc_b = (const float*)d_in[16];
  const float* lnq_g = (const float*)d_in[17];
  const float* lnq_b = (const float*)d_in[18];
  const float* lnk_g = (const float*)d_in[19];
  const float* lnk_b = (const float*)d_in[20];

  char* ws = (char*)d_ws;
  unsigned short* wfr = (unsigned short*)(ws + 0);          // 256 KB (fragment-order [We | Wck])
  float2* trig        = (float2*)(ws + 262144);             // 512 KB
  float* qhat         = (float*)(ws + 786432);              // 64 KB
  float* ckv          = (float*)(ws + 851968);              // 1 KB
  float* gkv          = (float*)(ws + 852992);              // 1 KB
  float* bkv          = (float*)(ws + 854016);              // 1 KB
  float2* sbuf        = (float2*)(ws + 855040);             // 4 KB
  float2* stats       = (float2*)(ws + 1048576);            // 1 MB
  float* scores       = (float*)(ws + 2097152);             // 8 MB
  float* wbuf         = (float*)(ws + 10485760);            // 8 MB
  float* ypart        = (float*)(ws + 18874368);            // 16 MB
  float* zbuf         = (float*)(ws + 35651584);            // 512 KB

  float* out = (float*)d_out;
  float* out_logits = out;                 // 32*40
  float* out_pooled = out + 1280;          // 32*256
  float* out_attn   = out + 9472;          // 32*2*256
  float* out_query  = out + 25856;         // 32*2*256

  prep1_kernel<<<289, 256, 0, stream>>>(eeg_w, k_w, lnk_g, eeg_b, lnk_b, k_b,
                                        wfr, trig, ckv, gkv, bkv);
  prep2_kernel<<<256, 256, 0, stream>>>(eeg_w, k_w, lnk_g, wfr);
  q_kernel<<<64, 256, 0, stream>>>(stim_feat, temp_feat, stim_w, stim_b,
                                   temp_w, temp_b, q_w, q_b, lnq_g, lnq_b,
                                   out_query, qhat);
  main2_kernel<<<4096, 256, 0, stream>>>(eeg_feat, eeg_b, wfr, trig, qhat,
                                         ckv, gkv, bkv, stats, scores);
  wgt_kernel<<<256, 256, 0, stream>>>(scores, stats, wbuf, sbuf);
  ysum_kernel<<<1024, 256, 0, stream>>>(eeg_feat, wbuf, ypart);
  yz_kernel<<<512, 256, 0, stream>>>(ypart, sbuf, eeg_w, eeg_b, lnk_g, lnk_b, zbuf);
  att_kernel<<<256, 256, 0, stream>>>(zbuf, v_w, v_b, out_attn, out_pooled);
  logit_kernel<<<32, 256, 0, stream>>>(out_pooled, fc_w, fc_b, out_logits);
}